// Round 16
// baseline (125.577 us; speedup 1.0000x reference)
//
#include <hip/hip_runtime.h>
#include <hip/hip_bf16.h>

#define B_ 8
#define N_ 2048
#define H_ 8
#define DM_ 512
#define NT_ 32   // N_/64 K-tiles total
#define NTH_ 16  // K-tiles per wave (half range)

typedef __bf16 bf16x8 __attribute__((ext_vector_type(8)));
typedef float f32x4 __attribute__((ext_vector_type(4)));
typedef float f32x16 __attribute__((ext_vector_type(16)));
typedef unsigned short us8 __attribute__((ext_vector_type(8)));
typedef unsigned short us4 __attribute__((ext_vector_type(4)));
typedef unsigned int u32x4 __attribute__((ext_vector_type(4)));

// fold 1/sqrt(64) * log2(e) into Q so softmax runs in exp2 domain
#define QSCALE 0.1803368801111204f

// LDS tiles (qkv/proj only): 64 bf16 per row = 128B stride, XOR-swizzled.
__device__ __forceinline__ int swz(int row, int byte_in_row) {
  return row * 128 + (byte_in_row ^ ((row & 7) << 4));
}

__device__ __forceinline__ unsigned short f2bf(float x) {
  __bf16 h = (__bf16)x;
  return __builtin_bit_cast(unsigned short, h);
}

__device__ __forceinline__ float fexp2(float x) {
#if __has_builtin(__builtin_amdgcn_exp2f)
  return __builtin_amdgcn_exp2f(x);
#else
  return exp2f(x);
#endif
}

__device__ __forceinline__ unsigned cvtpk(float a, float b) {
  unsigned r;
  asm("v_cvt_pk_bf16_f32 %0, %1, %2" : "=v"(r) : "v"(a), "v"(b));
  return r;
}

// Exchange: a -> {a.lo, b.lo}, b -> {a.hi, b.hi} (lane-aligned half swap).
__device__ __forceinline__ void plswap(unsigned& a, unsigned& b) {
#if __has_builtin(__builtin_amdgcn_permlane32_swap)
  auto r = __builtin_amdgcn_permlane32_swap(a, b, false, false);
  a = r[0];
  b = r[1];
#else
  asm("v_permlane32_swap_b32 %0, %1" : "+v"(a), "+v"(b));
#endif
}

__device__ __forceinline__ f32x4 mfma16(bf16x8 a, bf16x8 b, f32x4 c) {
  return __builtin_amdgcn_mfma_f32_16x16x32_bf16(a, b, c, 0, 0, 0);
}
__device__ __forceinline__ f32x16 mfma32(bf16x8 a, bf16x8 b, f32x16 c) {
  return __builtin_amdgcn_mfma_f32_32x32x16_bf16(a, b, c, 0, 0, 0);
}

__device__ __forceinline__ bf16x8 ldg8(const unsigned short* p) {
  return *reinterpret_cast<const bf16x8*>(p);
}

// Stage a 64x64 f32 tile into LDS as bf16, swizzled. 256 threads.
__device__ __forceinline__ void stage_f32_tile(const float* __restrict__ src,
                                               int src_stride, char* dst, int t) {
#pragma unroll
  for (int rep = 0; rep < 4; ++rep) {
    int cid = rep * 256 + t;
    int row = cid >> 4, c4 = cid & 15;
    float4 v = *reinterpret_cast<const float4*>(src + (size_t)row * src_stride + c4 * 4);
    us4 o;
    o[0] = f2bf(v.x); o[1] = f2bf(v.y); o[2] = f2bf(v.z); o[3] = f2bf(v.w);
    *reinterpret_cast<us4*>(dst + row * 128 + ((c4 * 8) ^ ((row & 7) << 4))) = o;
  }
}

__device__ __forceinline__ void stage_bf16_tile(const unsigned short* __restrict__ src,
                                                int src_stride, char* dst, int t) {
#pragma unroll
  for (int rep = 0; rep < 2; ++rep) {
    int cid = rep * 256 + t;
    int row = cid >> 3, c = cid & 7;
    us8 v = *reinterpret_cast<const us8*>(src + (size_t)row * src_stride + c * 8);
    *reinterpret_cast<us8*>(dst + row * 128 + ((c * 16) ^ ((row & 7) << 4))) = v;
  }
}

// softmax (m==0, exp2 domain) + T12 repack of one 64x32 S^T pair.
// Pure by-value SSA (no reference arrays — R4 lesson). Matches R9 verified code.
struct PF {
  bf16x8 p0, p1, p2, p3;
  float ls;
};
__device__ __forceinline__ PF softrepack(f32x16 s0, f32x16 s1) {
  float ts0 = 0.f, ts1 = 0.f, ts2 = 0.f, ts3 = 0.f;
#pragma unroll
  for (int r = 0; r < 16; r += 4) {
    s0[r + 0] = fexp2(s0[r + 0]); ts0 += s0[r + 0];
    s0[r + 1] = fexp2(s0[r + 1]); ts1 += s0[r + 1];
    s0[r + 2] = fexp2(s0[r + 2]); ts2 += s0[r + 2];
    s0[r + 3] = fexp2(s0[r + 3]); ts3 += s0[r + 3];
    s1[r + 0] = fexp2(s1[r + 0]); ts0 += s1[r + 0];
    s1[r + 1] = fexp2(s1[r + 1]); ts1 += s1[r + 1];
    s1[r + 2] = fexp2(s1[r + 2]); ts2 += s1[r + 2];
    s1[r + 3] = fexp2(s1[r + 3]); ts3 += s1[r + 3];
  }
  unsigned pl0[4], ph0[4], pl1[4], ph1[4];
#pragma unroll
  for (int qi = 0; qi < 4; ++qi) {
    pl0[qi] = cvtpk(s0[4 * qi + 0], s0[4 * qi + 1]);
    ph0[qi] = cvtpk(s0[4 * qi + 2], s0[4 * qi + 3]);
    pl1[qi] = cvtpk(s1[4 * qi + 0], s1[4 * qi + 1]);
    ph1[qi] = cvtpk(s1[4 * qi + 2], s1[4 * qi + 3]);
  }
  // after swap: X[2p] = {lo-half own, partner lo} = A-words (j0..3),
  //             X[2p+1] = {hi-half pair}          = B-words (j4..7)
  plswap(pl0[0], pl0[1]); plswap(ph0[0], ph0[1]);
  plswap(pl0[2], pl0[3]); plswap(ph0[2], ph0[3]);
  plswap(pl1[0], pl1[1]); plswap(ph1[0], ph1[1]);
  plswap(pl1[2], pl1[3]); plswap(ph1[2], ph1[3]);
  PF o;
  u32x4 w0 = {pl0[0], ph0[0], pl0[1], ph0[1]};
  u32x4 w1 = {pl0[2], ph0[2], pl0[3], ph0[3]};
  u32x4 w2 = {pl1[0], ph1[0], pl1[1], ph1[1]};
  u32x4 w3 = {pl1[2], ph1[2], pl1[3], ph1[3]};
  o.p0 = __builtin_bit_cast(bf16x8, w0);
  o.p1 = __builtin_bit_cast(bf16x8, w1);
  o.p2 = __builtin_bit_cast(bf16x8, w2);
  o.p3 = __builtin_bit_cast(bf16x8, w3);
  o.ls = (ts0 + ts1) + (ts2 + ts3);
  return o;
}

// ---------------------------------------------------------------------------
// Kernel A: per-head QKV projection (LDS-staged, verified) — 128-row blocks,
// W tiles staged once per block. Outputs in MFMA-FRAGMENT order:
//  Qf/Kf element (n,e): (n>>5)*2048 + (e>>4)*512 + ((e>>3)&1)*256 + (n&31)*8 + (e&7)
//  Vf element (n=k, e=d): (n>>6)*4096 + (e>>5)*2048 + ((n>>4)&3)*512
//                          + ((n>>3)&1)*256 + (e&31)*8 + (n&7)
// ---------------------------------------------------------------------------
__global__ __launch_bounds__(256, 4) void qkv_kernel(
    const float* __restrict__ x,
    const float* __restrict__ Wq, const float* __restrict__ bq,
    const float* __restrict__ Wk, const float* __restrict__ bk,
    const float* __restrict__ Wv, const float* __restrict__ bv,
    unsigned short* __restrict__ Qf, unsigned short* __restrict__ Kf,
    unsigned short* __restrict__ Vf) {
  __shared__ __align__(16) char sX[8192];
  __shared__ __align__(16) char sWq[8192];
  __shared__ __align__(16) char sWk[8192];
  __shared__ __align__(16) char sWv[8192];

  const int t = threadIdx.x;
  const int bh = blockIdx.y, h = bh & 7, b = bh >> 3;
  const int lane = t & 63, w = t >> 6, g = lane >> 4, li = lane & 15;

  stage_f32_tile(Wq + (size_t)h * 4096, 64, sWq, t);
  stage_f32_tile(Wk + (size_t)h * 4096, 64, sWk, t);
  stage_f32_tile(Wv + (size_t)h * 4096, 64, sWv, t);

  const size_t seg = (size_t)N_ * 64;
  unsigned short* Qs = Qf + (size_t)bh * seg;
  unsigned short* Ks = Kf + (size_t)bh * seg;
  unsigned short* Vs = Vf + (size_t)bh * seg;

#pragma unroll 1
  for (int half = 0; half < 2; ++half) {
    const int n0 = blockIdx.x * 128 + half * 64;

    __syncthreads();  // protect sX reuse (and W tiles on first pass)
    stage_f32_tile(x + ((size_t)(b * N_ + n0)) * DM_ + h * 64, DM_, sX, t);
    __syncthreads();

    bf16x8 xa0 = *reinterpret_cast<const bf16x8*>(sX + swz(16 * w + li, 16 * g));
    bf16x8 xa1 = *reinterpret_cast<const bf16x8*>(sX + swz(16 * w + li, 64 + 16 * g));

    const int qkbase =
        ((n0 >> 5) + (w >> 1)) * 2048 + (li >> 3) * 256 + (w & 1) * 128 + (li & 7);
    const int vbase =
        (n0 >> 6) * 4096 + w * 512 + (g >> 1) * 256 + 4 * (g & 1) + li * 8;

#pragma unroll
    for (int c = 0; c < 4; ++c) {
      f32x4 a = {0.f, 0.f, 0.f, 0.f};
      bf16x8 b0 = *reinterpret_cast<const bf16x8*>(sWq + swz(c * 16 + li, 16 * g));
      bf16x8 b1 = *reinterpret_cast<const bf16x8*>(sWq + swz(c * 16 + li, 64 + 16 * g));
      a = mfma16(xa0, b0, a);
      a = mfma16(xa1, b1, a);
      float bb = bq[h * 64 + c * 16 + li];
#pragma unroll
      for (int i = 0; i < 4; ++i)
        Qs[qkbase + c * 512 + (4 * g + i) * 8] = f2bf((a[i] + bb) * QSCALE);
    }
#pragma unroll
    for (int c = 0; c < 4; ++c) {
      f32x4 a = {0.f, 0.f, 0.f, 0.f};
      bf16x8 b0 = *reinterpret_cast<const bf16x8*>(sWk + swz(c * 16 + li, 16 * g));
      bf16x8 b1 = *reinterpret_cast<const bf16x8*>(sWk + swz(c * 16 + li, 64 + 16 * g));
      a = mfma16(xa0, b0, a);
      a = mfma16(xa1, b1, a);
      float bb = bk[h * 64 + c * 16 + li];
#pragma unroll
      for (int i = 0; i < 4; ++i)
        Ks[qkbase + c * 512 + (4 * g + i) * 8] = f2bf(a[i] + bb);
    }
#pragma unroll
    for (int c = 0; c < 4; ++c) {
      f32x4 a = {0.f, 0.f, 0.f, 0.f};
      bf16x8 b0 = *reinterpret_cast<const bf16x8*>(sWv + swz(c * 16 + li, 16 * g));
      bf16x8 b1 = *reinterpret_cast<const bf16x8*>(sWv + swz(c * 16 + li, 64 + 16 * g));
      a = mfma16(xa0, b0, a);
      a = mfma16(xa1, b1, a);
      float bb = bv[h * 64 + c * 16 + li];
      us4 pk;
#pragma unroll
      for (int i = 0; i < 4; ++i) pk[i] = f2bf(a[i] + bb);
      *reinterpret_cast<us4*>(Vs + vbase + (c >> 1) * 2048 + (c & 1) * 128) = pk;
    }
  }
}

// ---------------------------------------------------------------------------
// Kernel B: flash attention — FROZEN R15 (verified best: 84 us). q x2 per
// wave against shared kf/vf registers (32 MFMA + 2 softmaxes per 16KB K/V
// tile); k-split x2; m == 0 softmax -> additive partials; two-pass LDS merge.
// __launch_bounds__(256,2): q x3/x4 exceeds the 256-reg budget (next cliff).
// ---------------------------------------------------------------------------
__global__ __launch_bounds__(256, 2) void attn_kernel(
    const unsigned short* __restrict__ Qf, const unsigned short* __restrict__ Kf,
    const unsigned short* __restrict__ Vf, unsigned short* __restrict__ AOw) {
  __shared__ float mo[2][32][64];  // [p][j][lane] — lane-contiguous
  __shared__ float ml[2][64];

  const int t = threadIdx.x;
  const int lane = t & 63, w = t >> 6;
  const int lo = lane & 31;
  const int p = w & 1, kh = w >> 1;

  // XCD swizzle: 1024 blocks = 8 XCDs x 128 (bijective); each XCD gets 8
  // consecutive bh's worth of work -> K/V L2 locality.
  const int bid = blockIdx.x;
  const int work = (bid & 7) * 128 + (bid >> 3);
  const int bh = work >> 4;
  const int qq = work & 15;          // q-quad (4 q-blocks) of this block
  const int qb0 = qq * 4 + 2 * p;    // this wave's first 32-row q-block
  const int h = bh & 7, b = bh >> 3;

  const size_t seg = (size_t)N_ * 64;
  const unsigned short* qp = Qf + (size_t)bh * seg + qb0 * 2048 + lane * 8;
  const unsigned short* kp =
      Kf + (size_t)bh * seg + (size_t)kh * NTH_ * 4096 + lane * 8;
  const unsigned short* vp =
      Vf + (size_t)bh * seg + (size_t)kh * NTH_ * 4096 + lane * 8;

  bf16x8 qf0[4], qf1[4];
#pragma unroll
  for (int dd = 0; dd < 4; ++dd) {
    qf0[dd] = ldg8(qp + dd * 512);
    qf1[dd] = ldg8(qp + 2048 + dd * 512);
  }

  // single-buffer K fragment registers; prologue fills first tile of my half
  bf16x8 kf[8], vf[8];
#pragma unroll
  for (int j = 0; j < 8; ++j) kf[j] = ldg8(kp + j * 512);

  f32x16 o0 = {}, o1 = {}, o2 = {}, o3 = {};
  float l0 = 0.f, l1 = 0.f;

#pragma unroll 1
  for (int kt = 0; kt < NTH_; ++kt) {
    // V fragments for THIS tile: issue now, consume at PV-A (~400 cyc away).
    {
      const unsigned short* vpt = vp + (size_t)kt * 4096;
#pragma unroll
      for (int j = 0; j < 8; ++j) vf[j] = ldg8(vpt + j * 512);
    }
    __builtin_amdgcn_sched_barrier(0);  // pin: V loads stay issued here

    // ---- q-block A: S = K Q0^T ----
    f32x16 s0 = {}, s1 = {};
    __builtin_amdgcn_s_setprio(1);
#pragma unroll
    for (int dd = 0; dd < 4; ++dd) {
      s0 = mfma32(kf[dd], qf0[dd], s0);
      s1 = mfma32(kf[4 + dd], qf0[dd], s1);
    }
    __builtin_amdgcn_s_setprio(0);

    PF A = softrepack(s0, s1);
    l0 += A.ls;

    __builtin_amdgcn_s_setprio(1);
    o0 = mfma32(vf[0], A.p0, o0); o1 = mfma32(vf[4], A.p0, o1);
    o0 = mfma32(vf[1], A.p1, o0); o1 = mfma32(vf[5], A.p1, o1);
    o0 = mfma32(vf[2], A.p2, o0); o1 = mfma32(vf[6], A.p2, o1);
    o0 = mfma32(vf[3], A.p3, o0); o1 = mfma32(vf[7], A.p3, o1);
    __builtin_amdgcn_s_setprio(0);

    // ---- q-block B: S = K Q1^T (last kf use) ----
    f32x16 r0 = {}, r1 = {};
    __builtin_amdgcn_s_setprio(1);
#pragma unroll
    for (int dd = 0; dd < 4; ++dd) {
      r0 = mfma32(kf[dd], qf1[dd], r0);
      r1 = mfma32(kf[4 + dd], qf1[dd], r1);
    }
    __builtin_amdgcn_s_setprio(0);

    // prefetch next tile's K into the just-consumed registers
    if (kt + 1 < NTH_) {
      const unsigned short* kpt = kp + (size_t)(kt + 1) * 4096;
#pragma unroll
      for (int j = 0; j < 8; ++j) kf[j] = ldg8(kpt + j * 512);
    }
    __builtin_amdgcn_sched_barrier(0);  // pin: K prefetch stays issued here

    PF Bf = softrepack(r0, r1);
    l1 += Bf.ls;

    __builtin_amdgcn_s_setprio(1);
    o2 = mfma32(vf[0], Bf.p0, o2); o3 = mfma32(vf[4], Bf.p0, o3);
    o2 = mfma32(vf[1], Bf.p1, o2); o3 = mfma32(vf[5], Bf.p1, o3);
    o2 = mfma32(vf[2], Bf.p2, o2); o3 = mfma32(vf[6], Bf.p2, o3);
    o2 = mfma32(vf[3], Bf.p3, o2); o3 = mfma32(vf[7], Bf.p3, o3);
    __builtin_amdgcn_s_setprio(0);
  }

  // two-pass merge of kh partials via LDS (m == 0 -> purely additive)
  // pass 1: q-block A
  if (kh) {
#pragma unroll
    for (int j = 0; j < 16; ++j) {
      mo[p][j][lane] = o0[j];
      mo[p][16 + j][lane] = o1[j];
    }
    ml[p][lane] = l0;
  }
  __syncthreads();
  if (!kh) {
#pragma unroll
    for (int j = 0; j < 16; ++j) {
      o0[j] += mo[p][j][lane];
      o1[j] += mo[p][16 + j][lane];
    }
    l0 += ml[p][lane];
  }
  __syncthreads();
  // pass 2: q-block B
  if (kh) {
#pragma unroll
    for (int j = 0; j < 16; ++j) {
      mo[p][j][lane] = o2[j];
      mo[p][16 + j][lane] = o3[j];
    }
    ml[p][lane] = l1;
  }
  __syncthreads();
  if (kh) return;
#pragma unroll
  for (int j = 0; j < 16; ++j) {
    o2[j] += mo[p][j][lane];
    o3[j] += mo[p][16 + j][lane];
  }
  l1 += ml[p][lane];

  // epilogue: combine l halves, normalize, store O^T for both q-blocks
  l0 += __shfl_xor(l0, 32);
  l1 += __shfl_xor(l1, 32);
  const int hi = lane >> 5;
  const float invl0 = 1.0f / l0;
  const float invl1 = 1.0f / l1;
  unsigned short* aoptr0 =
      AOw + ((size_t)(b * N_) + qb0 * 32 + lo) * DM_ + h * 64 + 4 * hi;
  unsigned short* aoptr1 = aoptr0 + (size_t)32 * DM_;
#pragma unroll
  for (int qi = 0; qi < 4; ++qi) {
    us4 pk;
#pragma unroll
    for (int rr = 0; rr < 4; ++rr) pk[rr] = f2bf(o0[4 * qi + rr] * invl0);
    *reinterpret_cast<us4*>(aoptr0 + 8 * qi) = pk;
  }
#pragma unroll
  for (int qi = 0; qi < 4; ++qi) {
    us4 pk;
#pragma unroll
    for (int rr = 0; rr < 4; ++rr) pk[rr] = f2bf(o1[4 * qi + rr] * invl0);
    *reinterpret_cast<us4*>(aoptr0 + 32 + 8 * qi) = pk;
  }
#pragma unroll
  for (int qi = 0; qi < 4; ++qi) {
    us4 pk;
#pragma unroll
    for (int rr = 0; rr < 4; ++rr) pk[rr] = f2bf(o2[4 * qi + rr] * invl1);
    *reinterpret_cast<us4*>(aoptr1 + 8 * qi) = pk;
  }
#pragma unroll
  for (int qi = 0; qi < 4; ++qi) {
    us4 pk;
#pragma unroll
    for (int rr = 0; rr < 4; ++rr) pk[rr] = f2bf(o3[4 * qi + rr] * invl1);
    *reinterpret_cast<us4*>(aoptr1 + 32 + 8 * qi) = pk;
  }
}

// ---------------------------------------------------------------------------
// Kernel C: output projection  out = AO @ Wp^T + bp  (f32 out) — LDS-staged
// (no-LDS variant was 10x slower: R13), now with 128-ROW BLOCKS: two 64-row
// AO tiles share each staged Wp tile (halves Wp L2 restaging; same trick as
// qkv R14). Grid (128, 8).
// ---------------------------------------------------------------------------
__global__ __launch_bounds__(256, 4) void proj_kernel(
    const unsigned short* __restrict__ AOw, const float* __restrict__ Wp,
    const float* __restrict__ bp, float* __restrict__ out) {
  __shared__ __align__(16) char sA0[8192];
  __shared__ __align__(16) char sA1[8192];
  __shared__ __align__(16) char sB[8192];

  const int t = threadIdx.x;
  const int r0 = blockIdx.x * 128;
  const int i0 = blockIdx.y * 64;
  const int lane = t & 63, w = t >> 6, g = lane >> 4, li = lane & 15;

  f32x4 acc0[4], acc1[4];
#pragma unroll
  for (int c = 0; c < 4; ++c) {
    acc0[c][0] = 0.f; acc0[c][1] = 0.f; acc0[c][2] = 0.f; acc0[c][3] = 0.f;
    acc1[c][0] = 0.f; acc1[c][1] = 0.f; acc1[c][2] = 0.f; acc1[c][3] = 0.f;
  }

  for (int jt = 0; jt < 8; ++jt) {
    __syncthreads();
    stage_bf16_tile(AOw + (size_t)r0 * DM_ + jt * 64, DM_, sA0, t);
    stage_bf16_tile(AOw + (size_t)(r0 + 64) * DM_ + jt * 64, DM_, sA1, t);
    stage_f32_tile(Wp + (size_t)i0 * DM_ + jt * 64, DM_, sB, t);
    __syncthreads();

    bf16x8 a00 = *reinterpret_cast<const bf16x8*>(sA0 + swz(16 * w + li, 16 * g));
    bf16x8 a01 = *reinterpret_cast<const bf16x8*>(sA0 + swz(16 * w + li, 64 + 16 * g));
    bf16x8 a10 = *reinterpret_cast<const bf16x8*>(sA1 + swz(16 * w + li, 16 * g));
    bf16x8 a11 = *reinterpret_cast<const bf16x8*>(sA1 + swz(16 * w + li, 64 + 16 * g));
#pragma unroll
    for (int c = 0; c < 4; ++c) {
      bf16x8 b0 = *reinterpret_cast<const bf16x8*>(sB + swz(c * 16 + li, 16 * g));
      bf16x8 b1 = *reinterpret_cast<const bf16x8*>(sB + swz(c * 16 + li, 64 + 16 * g));
      acc0[c] = mfma16(a00, b0, acc0[c]);
      acc0[c] = mfma16(a01, b1, acc0[c]);
      acc1[c] = mfma16(a10, b0, acc1[c]);
      acc1[c] = mfma16(a11, b1, acc1[c]);
    }
  }

#pragma unroll
  for (int c = 0; c < 4; ++c) {
    float bb = bp[i0 + c * 16 + li];
#pragma unroll
    for (int i = 0; i < 4; ++i) {
      out[(size_t)(r0 + 16 * w + 4 * g + i) * DM_ + i0 + c * 16 + li] = acc0[c][i] + bb;
      out[(size_t)(r0 + 64 + 16 * w + 4 * g + i) * DM_ + i0 + c * 16 + li] = acc1[c][i] + bb;
    }
  }
}

extern "C" void kernel_launch(void* const* d_in, const int* in_sizes, int n_in,
                              void* d_out, int out_size, void* d_ws, size_t ws_size,
                              hipStream_t stream) {
  const float* x  = (const float*)d_in[0];
  const float* Wq = (const float*)d_in[1];
  const float* bq = (const float*)d_in[2];
  const float* Wk = (const float*)d_in[3];
  const float* bk = (const float*)d_in[4];
  const float* Wv = (const float*)d_in[5];
  const float* bv = (const float*)d_in[6];
  const float* Wp = (const float*)d_in[7];
  const float* bp = (const float*)d_in[8];
  float* out = (float*)d_out;

  const size_t seg = (size_t)B_ * H_ * N_ * 64;  // elements
  unsigned short* Qf  = (unsigned short*)d_ws;
  unsigned short* Kf  = Qf + seg;
  unsigned short* Vf  = Kf + seg;
  unsigned short* AOw = Vf + seg;

  qkv_kernel<<<dim3(16, 64), 256, 0, stream>>>(x, Wq, bq, Wk, bk, Wv, bv, Qf, Kf, Vf);
  attn_kernel<<<dim3(1024), 256, 0, stream>>>(Qf, Kf, Vf, AOw);
  proj_kernel<<<dim3(128, 8), 256, 0, stream>>>(AOw, Wp, bp, out);
}

// Round 17
// 122.272 us; speedup vs baseline: 1.0270x; 1.0270x over previous
//
#include <hip/hip_runtime.h>
#include <hip/hip_bf16.h>

#define B_ 8
#define N_ 2048
#define H_ 8
#define DM_ 512
#define NT_ 32   // N_/64 K-tiles total
#define NTH_ 16  // K-tiles per wave (half range)

typedef __bf16 bf16x8 __attribute__((ext_vector_type(8)));
typedef float f32x4 __attribute__((ext_vector_type(4)));
typedef float f32x16 __attribute__((ext_vector_type(16)));
typedef unsigned short us8 __attribute__((ext_vector_type(8)));
typedef unsigned short us4 __attribute__((ext_vector_type(4)));
typedef unsigned int u32x4 __attribute__((ext_vector_type(4)));

// fold 1/sqrt(64) * log2(e) into Q so softmax runs in exp2 domain
#define QSCALE 0.1803368801111204f

// LDS tiles (qkv/proj only): 64 bf16 per row = 128B stride, XOR-swizzled.
__device__ __forceinline__ int swz(int row, int byte_in_row) {
  return row * 128 + (byte_in_row ^ ((row & 7) << 4));
}

__device__ __forceinline__ unsigned short f2bf(float x) {
  __bf16 h = (__bf16)x;
  return __builtin_bit_cast(unsigned short, h);
}

__device__ __forceinline__ float fexp2(float x) {
#if __has_builtin(__builtin_amdgcn_exp2f)
  return __builtin_amdgcn_exp2f(x);
#else
  return exp2f(x);
#endif
}

__device__ __forceinline__ unsigned cvtpk(float a, float b) {
  unsigned r;
  asm("v_cvt_pk_bf16_f32 %0, %1, %2" : "=v"(r) : "v"(a), "v"(b));
  return r;
}

// Exchange: a -> {a.lo, b.lo}, b -> {a.hi, b.hi} (lane-aligned half swap).
__device__ __forceinline__ void plswap(unsigned& a, unsigned& b) {
#if __has_builtin(__builtin_amdgcn_permlane32_swap)
  auto r = __builtin_amdgcn_permlane32_swap(a, b, false, false);
  a = r[0];
  b = r[1];
#else
  asm("v_permlane32_swap_b32 %0, %1" : "+v"(a), "+v"(b));
#endif
}

__device__ __forceinline__ f32x4 mfma16(bf16x8 a, bf16x8 b, f32x4 c) {
  return __builtin_amdgcn_mfma_f32_16x16x32_bf16(a, b, c, 0, 0, 0);
}
__device__ __forceinline__ f32x16 mfma32(bf16x8 a, bf16x8 b, f32x16 c) {
  return __builtin_amdgcn_mfma_f32_32x32x16_bf16(a, b, c, 0, 0, 0);
}

__device__ __forceinline__ bf16x8 ldg8(const unsigned short* p) {
  return *reinterpret_cast<const bf16x8*>(p);
}

// Stage a 64x64 f32 tile into LDS as bf16, swizzled. 256 threads.
__device__ __forceinline__ void stage_f32_tile(const float* __restrict__ src,
                                               int src_stride, char* dst, int t) {
#pragma unroll
  for (int rep = 0; rep < 4; ++rep) {
    int cid = rep * 256 + t;
    int row = cid >> 4, c4 = cid & 15;
    float4 v = *reinterpret_cast<const float4*>(src + (size_t)row * src_stride + c4 * 4);
    us4 o;
    o[0] = f2bf(v.x); o[1] = f2bf(v.y); o[2] = f2bf(v.z); o[3] = f2bf(v.w);
    *reinterpret_cast<us4*>(dst + row * 128 + ((c4 * 8) ^ ((row & 7) << 4))) = o;
  }
}

__device__ __forceinline__ void stage_bf16_tile(const unsigned short* __restrict__ src,
                                                int src_stride, char* dst, int t) {
#pragma unroll
  for (int rep = 0; rep < 2; ++rep) {
    int cid = rep * 256 + t;
    int row = cid >> 3, c = cid & 7;
    us8 v = *reinterpret_cast<const us8*>(src + (size_t)row * src_stride + c * 8);
    *reinterpret_cast<us8*>(dst + row * 128 + ((c * 16) ^ ((row & 7) << 4))) = v;
  }
}

// softmax (m==0, exp2 domain) + T12 repack of one 64x32 S^T pair.
// Pure by-value SSA (no reference arrays — R4 lesson). Matches R9 verified code.
struct PF {
  bf16x8 p0, p1, p2, p3;
  float ls;
};
__device__ __forceinline__ PF softrepack(f32x16 s0, f32x16 s1) {
  float ts0 = 0.f, ts1 = 0.f, ts2 = 0.f, ts3 = 0.f;
#pragma unroll
  for (int r = 0; r < 16; r += 4) {
    s0[r + 0] = fexp2(s0[r + 0]); ts0 += s0[r + 0];
    s0[r + 1] = fexp2(s0[r + 1]); ts1 += s0[r + 1];
    s0[r + 2] = fexp2(s0[r + 2]); ts2 += s0[r + 2];
    s0[r + 3] = fexp2(s0[r + 3]); ts3 += s0[r + 3];
    s1[r + 0] = fexp2(s1[r + 0]); ts0 += s1[r + 0];
    s1[r + 1] = fexp2(s1[r + 1]); ts1 += s1[r + 1];
    s1[r + 2] = fexp2(s1[r + 2]); ts2 += s1[r + 2];
    s1[r + 3] = fexp2(s1[r + 3]); ts3 += s1[r + 3];
  }
  unsigned pl0[4], ph0[4], pl1[4], ph1[4];
#pragma unroll
  for (int qi = 0; qi < 4; ++qi) {
    pl0[qi] = cvtpk(s0[4 * qi + 0], s0[4 * qi + 1]);
    ph0[qi] = cvtpk(s0[4 * qi + 2], s0[4 * qi + 3]);
    pl1[qi] = cvtpk(s1[4 * qi + 0], s1[4 * qi + 1]);
    ph1[qi] = cvtpk(s1[4 * qi + 2], s1[4 * qi + 3]);
  }
  // after swap: X[2p] = {lo-half own, partner lo} = A-words (j0..3),
  //             X[2p+1] = {hi-half pair}          = B-words (j4..7)
  plswap(pl0[0], pl0[1]); plswap(ph0[0], ph0[1]);
  plswap(pl0[2], pl0[3]); plswap(ph0[2], ph0[3]);
  plswap(pl1[0], pl1[1]); plswap(ph1[0], ph1[1]);
  plswap(pl1[2], pl1[3]); plswap(ph1[2], ph1[3]);
  PF o;
  u32x4 w0 = {pl0[0], ph0[0], pl0[1], ph0[1]};
  u32x4 w1 = {pl0[2], ph0[2], pl0[3], ph0[3]};
  u32x4 w2 = {pl1[0], ph1[0], pl1[1], ph1[1]};
  u32x4 w3 = {pl1[2], ph1[2], pl1[3], ph1[3]};
  o.p0 = __builtin_bit_cast(bf16x8, w0);
  o.p1 = __builtin_bit_cast(bf16x8, w1);
  o.p2 = __builtin_bit_cast(bf16x8, w2);
  o.p3 = __builtin_bit_cast(bf16x8, w3);
  o.ls = (ts0 + ts1) + (ts2 + ts3);
  return o;
}

// ---------------------------------------------------------------------------
// Kernel A: per-head QKV projection (LDS-staged, verified) — 128-row blocks,
// W tiles staged once per block. Outputs in MFMA-FRAGMENT order:
//  Qf/Kf element (n,e): (n>>5)*2048 + (e>>4)*512 + ((e>>3)&1)*256 + (n&31)*8 + (e&7)
//  Vf element (n=k, e=d): (n>>6)*4096 + (e>>5)*2048 + ((n>>4)&3)*512
//                          + ((n>>3)&1)*256 + (e&31)*8 + (n&7)
// ---------------------------------------------------------------------------
__global__ __launch_bounds__(256, 4) void qkv_kernel(
    const float* __restrict__ x,
    const float* __restrict__ Wq, const float* __restrict__ bq,
    const float* __restrict__ Wk, const float* __restrict__ bk,
    const float* __restrict__ Wv, const float* __restrict__ bv,
    unsigned short* __restrict__ Qf, unsigned short* __restrict__ Kf,
    unsigned short* __restrict__ Vf) {
  __shared__ __align__(16) char sX[8192];
  __shared__ __align__(16) char sWq[8192];
  __shared__ __align__(16) char sWk[8192];
  __shared__ __align__(16) char sWv[8192];

  const int t = threadIdx.x;
  const int bh = blockIdx.y, h = bh & 7, b = bh >> 3;
  const int lane = t & 63, w = t >> 6, g = lane >> 4, li = lane & 15;

  stage_f32_tile(Wq + (size_t)h * 4096, 64, sWq, t);
  stage_f32_tile(Wk + (size_t)h * 4096, 64, sWk, t);
  stage_f32_tile(Wv + (size_t)h * 4096, 64, sWv, t);

  const size_t seg = (size_t)N_ * 64;
  unsigned short* Qs = Qf + (size_t)bh * seg;
  unsigned short* Ks = Kf + (size_t)bh * seg;
  unsigned short* Vs = Vf + (size_t)bh * seg;

#pragma unroll 1
  for (int half = 0; half < 2; ++half) {
    const int n0 = blockIdx.x * 128 + half * 64;

    __syncthreads();  // protect sX reuse (and W tiles on first pass)
    stage_f32_tile(x + ((size_t)(b * N_ + n0)) * DM_ + h * 64, DM_, sX, t);
    __syncthreads();

    bf16x8 xa0 = *reinterpret_cast<const bf16x8*>(sX + swz(16 * w + li, 16 * g));
    bf16x8 xa1 = *reinterpret_cast<const bf16x8*>(sX + swz(16 * w + li, 64 + 16 * g));

    const int qkbase =
        ((n0 >> 5) + (w >> 1)) * 2048 + (li >> 3) * 256 + (w & 1) * 128 + (li & 7);
    const int vbase =
        (n0 >> 6) * 4096 + w * 512 + (g >> 1) * 256 + 4 * (g & 1) + li * 8;

#pragma unroll
    for (int c = 0; c < 4; ++c) {
      f32x4 a = {0.f, 0.f, 0.f, 0.f};
      bf16x8 b0 = *reinterpret_cast<const bf16x8*>(sWq + swz(c * 16 + li, 16 * g));
      bf16x8 b1 = *reinterpret_cast<const bf16x8*>(sWq + swz(c * 16 + li, 64 + 16 * g));
      a = mfma16(xa0, b0, a);
      a = mfma16(xa1, b1, a);
      float bb = bq[h * 64 + c * 16 + li];
#pragma unroll
      for (int i = 0; i < 4; ++i)
        Qs[qkbase + c * 512 + (4 * g + i) * 8] = f2bf((a[i] + bb) * QSCALE);
    }
#pragma unroll
    for (int c = 0; c < 4; ++c) {
      f32x4 a = {0.f, 0.f, 0.f, 0.f};
      bf16x8 b0 = *reinterpret_cast<const bf16x8*>(sWk + swz(c * 16 + li, 16 * g));
      bf16x8 b1 = *reinterpret_cast<const bf16x8*>(sWk + swz(c * 16 + li, 64 + 16 * g));
      a = mfma16(xa0, b0, a);
      a = mfma16(xa1, b1, a);
      float bb = bk[h * 64 + c * 16 + li];
#pragma unroll
      for (int i = 0; i < 4; ++i)
        Ks[qkbase + c * 512 + (4 * g + i) * 8] = f2bf(a[i] + bb);
    }
#pragma unroll
    for (int c = 0; c < 4; ++c) {
      f32x4 a = {0.f, 0.f, 0.f, 0.f};
      bf16x8 b0 = *reinterpret_cast<const bf16x8*>(sWv + swz(c * 16 + li, 16 * g));
      bf16x8 b1 = *reinterpret_cast<const bf16x8*>(sWv + swz(c * 16 + li, 64 + 16 * g));
      a = mfma16(xa0, b0, a);
      a = mfma16(xa1, b1, a);
      float bb = bv[h * 64 + c * 16 + li];
      us4 pk;
#pragma unroll
      for (int i = 0; i < 4; ++i) pk[i] = f2bf(a[i] + bb);
      *reinterpret_cast<us4*>(Vs + vbase + (c >> 1) * 2048 + (c & 1) * 128) = pk;
    }
  }
}

// ---------------------------------------------------------------------------
// Kernel B: flash attention — FROZEN R15 (verified best: 84 us). q x2 per
// wave against shared kf/vf registers (32 MFMA + 2 softmaxes per 16KB K/V
// tile); k-split x2; m == 0 softmax -> additive partials; two-pass LDS merge.
// __launch_bounds__(256,2): q x3/x4 exceeds the 256-reg budget (next cliff).
// ---------------------------------------------------------------------------
__global__ __launch_bounds__(256, 2) void attn_kernel(
    const unsigned short* __restrict__ Qf, const unsigned short* __restrict__ Kf,
    const unsigned short* __restrict__ Vf, unsigned short* __restrict__ AOw) {
  __shared__ float mo[2][32][64];  // [p][j][lane] — lane-contiguous
  __shared__ float ml[2][64];

  const int t = threadIdx.x;
  const int lane = t & 63, w = t >> 6;
  const int lo = lane & 31;
  const int p = w & 1, kh = w >> 1;

  // XCD swizzle: 1024 blocks = 8 XCDs x 128 (bijective); each XCD gets 8
  // consecutive bh's worth of work -> K/V L2 locality.
  const int bid = blockIdx.x;
  const int work = (bid & 7) * 128 + (bid >> 3);
  const int bh = work >> 4;
  const int qq = work & 15;          // q-quad (4 q-blocks) of this block
  const int qb0 = qq * 4 + 2 * p;    // this wave's first 32-row q-block
  const int h = bh & 7, b = bh >> 3;

  const size_t seg = (size_t)N_ * 64;
  const unsigned short* qp = Qf + (size_t)bh * seg + qb0 * 2048 + lane * 8;
  const unsigned short* kp =
      Kf + (size_t)bh * seg + (size_t)kh * NTH_ * 4096 + lane * 8;
  const unsigned short* vp =
      Vf + (size_t)bh * seg + (size_t)kh * NTH_ * 4096 + lane * 8;

  bf16x8 qf0[4], qf1[4];
#pragma unroll
  for (int dd = 0; dd < 4; ++dd) {
    qf0[dd] = ldg8(qp + dd * 512);
    qf1[dd] = ldg8(qp + 2048 + dd * 512);
  }

  // single-buffer K fragment registers; prologue fills first tile of my half
  bf16x8 kf[8], vf[8];
#pragma unroll
  for (int j = 0; j < 8; ++j) kf[j] = ldg8(kp + j * 512);

  f32x16 o0 = {}, o1 = {}, o2 = {}, o3 = {};
  float l0 = 0.f, l1 = 0.f;

#pragma unroll 1
  for (int kt = 0; kt < NTH_; ++kt) {
    // V fragments for THIS tile: issue now, consume at PV-A (~400 cyc away).
    {
      const unsigned short* vpt = vp + (size_t)kt * 4096;
#pragma unroll
      for (int j = 0; j < 8; ++j) vf[j] = ldg8(vpt + j * 512);
    }
    __builtin_amdgcn_sched_barrier(0);  // pin: V loads stay issued here

    // ---- q-block A: S = K Q0^T ----
    f32x16 s0 = {}, s1 = {};
    __builtin_amdgcn_s_setprio(1);
#pragma unroll
    for (int dd = 0; dd < 4; ++dd) {
      s0 = mfma32(kf[dd], qf0[dd], s0);
      s1 = mfma32(kf[4 + dd], qf0[dd], s1);
    }
    __builtin_amdgcn_s_setprio(0);

    PF A = softrepack(s0, s1);
    l0 += A.ls;

    __builtin_amdgcn_s_setprio(1);
    o0 = mfma32(vf[0], A.p0, o0); o1 = mfma32(vf[4], A.p0, o1);
    o0 = mfma32(vf[1], A.p1, o0); o1 = mfma32(vf[5], A.p1, o1);
    o0 = mfma32(vf[2], A.p2, o0); o1 = mfma32(vf[6], A.p2, o1);
    o0 = mfma32(vf[3], A.p3, o0); o1 = mfma32(vf[7], A.p3, o1);
    __builtin_amdgcn_s_setprio(0);

    // ---- q-block B: S = K Q1^T (last kf use) ----
    f32x16 r0 = {}, r1 = {};
    __builtin_amdgcn_s_setprio(1);
#pragma unroll
    for (int dd = 0; dd < 4; ++dd) {
      r0 = mfma32(kf[dd], qf1[dd], r0);
      r1 = mfma32(kf[4 + dd], qf1[dd], r1);
    }
    __builtin_amdgcn_s_setprio(0);

    // prefetch next tile's K into the just-consumed registers
    if (kt + 1 < NTH_) {
      const unsigned short* kpt = kp + (size_t)(kt + 1) * 4096;
#pragma unroll
      for (int j = 0; j < 8; ++j) kf[j] = ldg8(kpt + j * 512);
    }
    __builtin_amdgcn_sched_barrier(0);  // pin: K prefetch stays issued here

    PF Bf = softrepack(r0, r1);
    l1 += Bf.ls;

    __builtin_amdgcn_s_setprio(1);
    o2 = mfma32(vf[0], Bf.p0, o2); o3 = mfma32(vf[4], Bf.p0, o3);
    o2 = mfma32(vf[1], Bf.p1, o2); o3 = mfma32(vf[5], Bf.p1, o3);
    o2 = mfma32(vf[2], Bf.p2, o2); o3 = mfma32(vf[6], Bf.p2, o3);
    o2 = mfma32(vf[3], Bf.p3, o2); o3 = mfma32(vf[7], Bf.p3, o3);
    __builtin_amdgcn_s_setprio(0);
  }

  // two-pass merge of kh partials via LDS (m == 0 -> purely additive)
  // pass 1: q-block A
  if (kh) {
#pragma unroll
    for (int j = 0; j < 16; ++j) {
      mo[p][j][lane] = o0[j];
      mo[p][16 + j][lane] = o1[j];
    }
    ml[p][lane] = l0;
  }
  __syncthreads();
  if (!kh) {
#pragma unroll
    for (int j = 0; j < 16; ++j) {
      o0[j] += mo[p][j][lane];
      o1[j] += mo[p][16 + j][lane];
    }
    l0 += ml[p][lane];
  }
  __syncthreads();
  // pass 2: q-block B
  if (kh) {
#pragma unroll
    for (int j = 0; j < 16; ++j) {
      mo[p][j][lane] = o2[j];
      mo[p][16 + j][lane] = o3[j];
    }
    ml[p][lane] = l1;
  }
  __syncthreads();
  if (kh) return;
#pragma unroll
  for (int j = 0; j < 16; ++j) {
    o2[j] += mo[p][j][lane];
    o3[j] += mo[p][16 + j][lane];
  }
  l1 += ml[p][lane];

  // epilogue: combine l halves, normalize, store O^T for both q-blocks
  l0 += __shfl_xor(l0, 32);
  l1 += __shfl_xor(l1, 32);
  const int hi = lane >> 5;
  const float invl0 = 1.0f / l0;
  const float invl1 = 1.0f / l1;
  unsigned short* aoptr0 =
      AOw + ((size_t)(b * N_) + qb0 * 32 + lo) * DM_ + h * 64 + 4 * hi;
  unsigned short* aoptr1 = aoptr0 + (size_t)32 * DM_;
#pragma unroll
  for (int qi = 0; qi < 4; ++qi) {
    us4 pk;
#pragma unroll
    for (int rr = 0; rr < 4; ++rr) pk[rr] = f2bf(o0[4 * qi + rr] * invl0);
    *reinterpret_cast<us4*>(aoptr0 + 8 * qi) = pk;
  }
#pragma unroll
  for (int qi = 0; qi < 4; ++qi) {
    us4 pk;
#pragma unroll
    for (int rr = 0; rr < 4; ++rr) pk[rr] = f2bf(o1[4 * qi + rr] * invl0);
    *reinterpret_cast<us4*>(aoptr0 + 32 + 8 * qi) = pk;
  }
#pragma unroll
  for (int qi = 0; qi < 4; ++qi) {
    us4 pk;
#pragma unroll
    for (int rr = 0; rr < 4; ++rr) pk[rr] = f2bf(o2[4 * qi + rr] * invl1);
    *reinterpret_cast<us4*>(aoptr1 + 8 * qi) = pk;
  }
#pragma unroll
  for (int qi = 0; qi < 4; ++qi) {
    us4 pk;
#pragma unroll
    for (int rr = 0; rr < 4; ++rr) pk[rr] = f2bf(o3[4 * qi + rr] * invl1);
    *reinterpret_cast<us4*>(aoptr1 + 32 + 8 * qi) = pk;
  }
}

// ---------------------------------------------------------------------------
// Kernel C: output projection  out = AO @ Wp^T + bp  (f32 out) — verified
// R9/R15 LDS-staged 64-row version (no-LDS was 10x slower R13; 128-row
// sharing was neutral-to-negative R16).
// ---------------------------------------------------------------------------
__global__ __launch_bounds__(256, 4) void proj_kernel(
    const unsigned short* __restrict__ AOw, const float* __restrict__ Wp,
    const float* __restrict__ bp, float* __restrict__ out) {
  __shared__ __align__(16) char sA[8192];
  __shared__ __align__(16) char sB[8192];

  const int t = threadIdx.x;
  const int r0 = blockIdx.x * 64;
  const int i0 = blockIdx.y * 64;
  const int lane = t & 63, w = t >> 6, g = lane >> 4, li = lane & 15;

  f32x4 acc[4];
#pragma unroll
  for (int c = 0; c < 4; ++c) {
    acc[c][0] = 0.f; acc[c][1] = 0.f; acc[c][2] = 0.f; acc[c][3] = 0.f;
  }

  for (int jt = 0; jt < 8; ++jt) {
    __syncthreads();
    stage_bf16_tile(AOw + (size_t)r0 * DM_ + jt * 64, DM_, sA, t);
    stage_f32_tile(Wp + (size_t)i0 * DM_ + jt * 64, DM_, sB, t);
    __syncthreads();

    bf16x8 a0 = *reinterpret_cast<const bf16x8*>(sA + swz(16 * w + li, 16 * g));
    bf16x8 a1 = *reinterpret_cast<const bf16x8*>(sA + swz(16 * w + li, 64 + 16 * g));
#pragma unroll
    for (int c = 0; c < 4; ++c) {
      bf16x8 b0 = *reinterpret_cast<const bf16x8*>(sB + swz(c * 16 + li, 16 * g));
      bf16x8 b1 = *reinterpret_cast<const bf16x8*>(sB + swz(c * 16 + li, 64 + 16 * g));
      acc[c] = mfma16(a0, b0, acc[c]);
      acc[c] = mfma16(a1, b1, acc[c]);
    }
  }

#pragma unroll
  for (int c = 0; c < 4; ++c) {
    float bb = bp[i0 + c * 16 + li];
#pragma unroll
    for (int i = 0; i < 4; ++i)
      out[(size_t)(r0 + 16 * w + 4 * g + i) * DM_ + i0 + c * 16 + li] = acc[c][i] + bb;
  }
}

extern "C" void kernel_launch(void* const* d_in, const int* in_sizes, int n_in,
                              void* d_out, int out_size, void* d_ws, size_t ws_size,
                              hipStream_t stream) {
  const float* x  = (const float*)d_in[0];
  const float* Wq = (const float*)d_in[1];
  const float* bq = (const float*)d_in[2];
  const float* Wk = (const float*)d_in[3];
  const float* bk = (const float*)d_in[4];
  const float* Wv = (const float*)d_in[5];
  const float* bv = (const float*)d_in[6];
  const float* Wp = (const float*)d_in[7];
  const float* bp = (const float*)d_in[8];
  float* out = (float*)d_out;

  const size_t seg = (size_t)B_ * H_ * N_ * 64;  // elements
  unsigned short* Qf  = (unsigned short*)d_ws;
  unsigned short* Kf  = Qf + seg;
  unsigned short* Vf  = Kf + seg;
  unsigned short* AOw = Vf + seg;

  qkv_kernel<<<dim3(16, 64), 256, 0, stream>>>(x, Wq, bq, Wk, bk, Wv, bv, Qf, Kf, Vf);
  attn_kernel<<<dim3(1024), 256, 0, stream>>>(Qf, Kf, Vf, AOw);
  proj_kernel<<<dim3(256, 8), 256, 0, stream>>>(AOw, Wp, bp, out);
}